// Round 12
// baseline (317.660 us; speedup 1.0000x reference)
//
#include <hip/hip_runtime.h>
#include <math.h>

#define BB 2
#define TT 2048
#define DD 2048
#define EE 8
#define CCv 512
#define OO1 256

typedef unsigned short u16;
typedef __bf16 bf16x8 __attribute__((ext_vector_type(8)));
typedef float f32x4 __attribute__((ext_vector_type(4)));

__device__ __forceinline__ u16 f2bf(float f) {
    unsigned u = __float_as_uint(f);
    unsigned r = (u + 0x7fffu + ((u >> 16) & 1u)) >> 16;
    return (u16)r;
}

__device__ __forceinline__ void gload16(const void* g, void* s) {
    __builtin_amdgcn_global_load_lds(
        (const __attribute__((address_space(1))) void*)g,
        (__attribute__((address_space(3))) void*)s, 16, 0, 0);
}

// ---------------- fp32 -> bf16 straight convert (vectorized) ----------------
__global__ __launch_bounds__(256) void conv_cast(const float* __restrict__ in,
                                                 u16* __restrict__ out, long n) {
    long i = ((long)blockIdx.x * 256 + threadIdx.x) * 4;
    float4 v = *(const float4*)&in[i];
    ushort4 o; o.x = f2bf(v.x); o.y = f2bf(v.y); o.z = f2bf(v.z); o.w = f2bf(v.w);
    *(ushort4*)&out[i] = o;
}

// ---------------- fp32 -> bf16 convert, write TWO copies (W1 per-batch dup) --
__global__ __launch_bounds__(256) void dup_cast(const float* __restrict__ in,
                                                u16* __restrict__ out, long dup) {
    long i = ((long)blockIdx.x * 256 + threadIdx.x) * 4;
    float4 v = *(const float4*)&in[i];
    ushort4 o; o.x = f2bf(v.x); o.y = f2bf(v.y); o.z = f2bf(v.z); o.w = f2bf(v.w);
    *(ushort4*)&out[i] = o;
    *(ushort4*)&out[i + dup] = o;
}

// ---------------- h = GELU(P0 + P1 + b1) -> bf16 (GEMM2 split-K fuse) -------
__global__ __launch_bounds__(256) void gelu_fuse(const float* __restrict__ P,
                                                 const float* __restrict__ b1,
                                                 u16* __restrict__ h) {
    long i = ((long)blockIdx.x * 256 + threadIdx.x) * 4;   // [z][c][o] flat
    const int o = (int)(i & 255);
    const int e = (int)((i >> 17) & 7);
    float4 a = *(const float4*)&P[i];
    float4 b = *(const float4*)&P[i + 4194304];
    float4 bb = *(const float4*)&b1[e * 256 + o];
    float r0 = a.x + b.x + bb.x, r1 = a.y + b.y + bb.y;
    float r2 = a.z + b.z + bb.z, r3 = a.w + b.w + bb.w;
    ushort4 o4;
    o4.x = f2bf(0.5f * r0 * (1.0f + erff(r0 * 0.70710678118654752f)));
    o4.y = f2bf(0.5f * r1 * (1.0f + erff(r1 * 0.70710678118654752f)));
    o4.z = f2bf(0.5f * r2 * (1.0f + erff(r2 * 0.70710678118654752f)));
    o4.w = f2bf(0.5f * r3 * (1.0f + erff(r3 * 0.70710678118654752f)));
    *(ushort4*)&h[i] = o4;
}

// ---------------- tiled transpose + convert: out[z][c][t] = in[z][t][c] -----
__global__ __launch_bounds__(256) void transpose_conv(
    const float* __restrict__ in, long inHi, long inLo, int modZ, long sIn,
    u16* __restrict__ out, long outZ, long sOut)
{
    __shared__ float tile[32][33];
    const int z = blockIdx.z;
    const float* ib = in + (long)(z / modZ) * inHi + (long)(z % modZ) * inLo;
    u16* ob = out + (long)z * outZ;
    const int t0 = blockIdx.y * 32, c0 = blockIdx.x * 32;
    const int tid = threadIdx.x;
    const int r = tid >> 3, c4 = (tid & 7) * 4;

    float4 v = *(const float4*)&ib[(long)(t0 + r) * sIn + c0 + c4];
    tile[r][c4 + 0] = v.x; tile[r][c4 + 1] = v.y;
    tile[r][c4 + 2] = v.z; tile[r][c4 + 3] = v.w;
    __syncthreads();

    const int oc = tid >> 3, t4 = (tid & 7) * 4;
    ushort4 o;
    o.x = f2bf(tile[t4 + 0][oc]);
    o.y = f2bf(tile[t4 + 1][oc]);
    o.z = f2bf(tile[t4 + 2][oc]);
    o.w = f2bf(tile[t4 + 3][oc]);
    *(ushort4*)&ob[(long)(c0 + oc) * sOut + t0 + t4] = o;
}

// ---------------- small 128x128 m97-structure GEMM (GEMM2 split-K / GEMM3) --
template<int EPI, int OUTBF>
__global__ __launch_bounds__(256)
void mfma_gemm(const u16* __restrict__ A, long ldA, long aHi, long aLo, int modA,
               const u16* __restrict__ B, long ldB, long bHi, long bLo, int modB,
               void* __restrict__ Cout, long ldC, long cHi, long cLo, int modC,
               const float* __restrict__ bias, long biasLo, int modBias,
               int M, int N, int K)
{
    __shared__ __align__(16) char smem[32768];
    char* smA = smem;
    char* smB = smem + 16384;

    const int z = blockIdx.z;
    const char* Ab = (const char*)(A + (long)(z / modA) * aHi + (long)(z % modA) * aLo);
    const char* Bb = (const char*)(B + (long)(z / modB) * bHi + (long)(z % modB) * bLo);
    const long ldAb = ldA * 2, ldBb = ldB * 2;

    const int m0 = blockIdx.y * 128, n0 = blockIdx.x * 128;
    const int tid = threadIdx.x;
    const int l = tid & 63;
    const int w = tid >> 6;
    const int wm = w >> 1, wn = w & 1;

    const int srow = l >> 3;
    const int schunk = (l & 7) ^ srow;
    const int frow = l & 15;
    const int fgrp = l >> 4;
    const int fch0 = fgrp ^ (l & 7);

    int aoff[4], boff[4];
#pragma unroll
    for (int i = 0; i < 4; ++i) {
        aoff[i] = (wm * 64 + i * 16 + frow) * 128 + fch0 * 16;
        boff[i] = (wn * 64 + i * 16 + frow) * 128 + fch0 * 16;
    }

    f32x4 acc[4][4];
    const f32x4 zero4 = {0.f, 0.f, 0.f, 0.f};
#pragma unroll
    for (int i = 0; i < 4; ++i)
#pragma unroll
        for (int j = 0; j < 4; ++j) acc[i][j] = zero4;

    const long sgo = (long)schunk * 16;

    for (int k0 = 0; k0 < K; k0 += 64) {
        const long kb = (long)k0 * 2;
#pragma unroll
        for (int j = 0; j < 4; ++j) {
            const int rr = (j * 4 + w) * 8 + srow;
            gload16(Ab + (long)(m0 + rr) * ldAb + kb + sgo, smA + (j * 4 + w) * 1024);
            gload16(Bb + (long)(n0 + rr) * ldBb + kb + sgo, smB + (j * 4 + w) * 1024);
        }
        __syncthreads();
#pragma unroll
        for (int kk = 0; kk < 2; ++kk) {
            const int kx = kk * 64;
            bf16x8 af[4], bfr[4];
#pragma unroll
            for (int i = 0; i < 4; ++i) af[i] = *(const bf16x8*)(smA + (aoff[i] ^ kx));
#pragma unroll
            for (int i = 0; i < 4; ++i) bfr[i] = *(const bf16x8*)(smB + (boff[i] ^ kx));
#pragma unroll
            for (int mi = 0; mi < 4; ++mi)
#pragma unroll
                for (int ni = 0; ni < 4; ++ni)
                    acc[mi][ni] = __builtin_amdgcn_mfma_f32_16x16x32_bf16(
                        af[mi], bfr[ni], acc[mi][ni], 0, 0, 0);
        }
        __syncthreads();
    }

    const long cbase = (long)(z / modC) * cHi + (long)(z % modC) * cLo;
    const float* biasB = (EPI != 0) ? (bias + (long)(z % modBias) * biasLo) : nullptr;
#pragma unroll
    for (int mi = 0; mi < 4; ++mi) {
#pragma unroll
        for (int ni = 0; ni < 4; ++ni) {
            const int col = n0 + wn * 64 + ni * 16 + frow;
            const int rowb = m0 + wm * 64 + mi * 16 + fgrp * 4;
#pragma unroll
            for (int r = 0; r < 4; ++r) {
                float v = acc[mi][ni][r];
                const int row = rowb + r;
                if (EPI == 3) v += biasB[row];
                const long idx = cbase + (long)row * ldC + col;
                if (OUTBF) ((u16*)Cout)[idx] = f2bf(v);
                else       ((float*)Cout)[idx] = v;
            }
        }
    }
}

// ---------------- 256x256 pipelined GEMM (GEMM1), r6/r9 gates, 16x16 MFMA ----
template<int OUTBF>
__global__ __launch_bounds__(512, 2)
void mfma_gemm_256(const u16* __restrict__ A, long ldA, long aHi, long aLo, int modA,
                   const u16* __restrict__ B, long ldB, long bHi, long bLo, int modB,
                   void* __restrict__ Cout, long ldC, long cHi, long cLo, int modC,
                   int M, int N, int K)
{
    __shared__ __align__(16) char smem[131072];   // 2 x (A0 A1 B0 B1) x 16KB

    const int z = blockIdx.z;
    const char* Ab = (const char*)(A + (long)(z / modA) * aHi + (long)(z % modA) * aLo);
    const char* Bb = (const char*)(B + (long)(z / modB) * bHi + (long)(z % modB) * bLo);
    const long ldAb = ldA * 2, ldBb = ldB * 2;

    const int m0 = blockIdx.y * 256, n0 = blockIdx.x * 256;
    const int tid = threadIdx.x;
    const int l = tid & 63;
    const int w = tid >> 6;
    const int wm = w >> 2, wn = w & 3;   // 2M x 4N

    const int srow = l >> 3;
    const int schunk = (l & 7) ^ srow;
    const long sgo = (long)schunk * 16;
    const int frow = l & 15, fgrp = l >> 4;
    const int cs0 = (fgrp ^ (l & 7)) * 16;

    auto stage = [&](int kt, int bsel, int half, int j) {
        const int rr = (w * 2 + j) * 8 + srow;
        const char* gb = (half < 2) ? Ab : Bb;
        const long ld = (half < 2) ? ldAb : ldBb;
        const int gr = ((half < 2) ? m0 + half * 128 : n0 + (half - 2) * 128) + rr;
        gload16(gb + (long)gr * ld + (long)kt * 128 + sgo,
                smem + bsel * 65536 + half * 16384 + (w * 2 + j) * 1024);
    };

    f32x4 acc[2][4][2][2];
    const f32x4 zero4 = {0.f, 0.f, 0.f, 0.f};
#pragma unroll
    for (int qm = 0; qm < 2; ++qm)
#pragma unroll
        for (int mi = 0; mi < 4; ++mi)
#pragma unroll
            for (int qn = 0; qn < 2; ++qn)
#pragma unroll
                for (int ni = 0; ni < 2; ++ni) acc[qm][mi][qn][ni] = zero4;

    int aoff[4], boff[2];
#pragma unroll
    for (int mi = 0; mi < 4; ++mi) aoff[mi] = (wm * 64 + mi * 16 + frow) * 128 + cs0;
#pragma unroll
    for (int ni = 0; ni < 2; ++ni) boff[ni] = (wn * 32 + ni * 16 + frow) * 128 + cs0;

    // prologue: stage tile 0 (order A0,B0,B1,A1)
    stage(0, 0, 0, 0); stage(0, 0, 0, 1);
    stage(0, 0, 2, 0); stage(0, 0, 2, 1);
    stage(0, 0, 3, 0); stage(0, 0, 3, 1);
    stage(0, 0, 1, 0); stage(0, 0, 1, 1);
    asm volatile("s_waitcnt vmcnt(4)" ::: "memory");   // A0,B0 landed
    __builtin_amdgcn_s_barrier();

    const int NT = K >> 6;
    for (int kt = 0; kt < NT; ++kt) {
        const char* buf = smem + (kt & 1) * 65536;
        const int sb = (kt & 1) ^ 1;
        const bool pf = (kt + 1) < NT;
        const int kn = kt + 1;
        bf16x8 af[4][2], bq0[2][2], bq1[2][2];

        // ---- p0: Q(0,0) — read A0 + B0; stage A0' ----
#pragma unroll
        for (int mi = 0; mi < 4; ++mi) {
            af[mi][0] = *(const bf16x8*)(buf + aoff[mi]);
            af[mi][1] = *(const bf16x8*)(buf + (aoff[mi] ^ 64));
        }
#pragma unroll
        for (int ni = 0; ni < 2; ++ni) {
            bq0[ni][0] = *(const bf16x8*)(buf + 32768 + boff[ni]);
            bq0[ni][1] = *(const bf16x8*)(buf + 32768 + (boff[ni] ^ 64));
        }
        if (pf) { stage(kn, sb, 0, 0); stage(kn, sb, 0, 1); }
        if (pf) { asm volatile("s_waitcnt vmcnt(4)" ::: "memory"); }
        else    { asm volatile("s_waitcnt vmcnt(2)" ::: "memory"); }
        __builtin_amdgcn_s_barrier();
        __builtin_amdgcn_s_setprio(1);
#pragma unroll
        for (int kk = 0; kk < 2; ++kk)
#pragma unroll
            for (int mi = 0; mi < 4; ++mi)
#pragma unroll
                for (int ni = 0; ni < 2; ++ni)
                    acc[0][mi][0][ni] = __builtin_amdgcn_mfma_f32_16x16x32_bf16(
                        af[mi][kk], bq0[ni][kk], acc[0][mi][0][ni], 0, 0, 0);
        __builtin_amdgcn_s_setprio(0);

        // ---- p1: Q(0,1) — read B1; stage B0' ----
#pragma unroll
        for (int ni = 0; ni < 2; ++ni) {
            bq1[ni][0] = *(const bf16x8*)(buf + 49152 + boff[ni]);
            bq1[ni][1] = *(const bf16x8*)(buf + 49152 + (boff[ni] ^ 64));
        }
        if (pf) { stage(kn, sb, 2, 0); stage(kn, sb, 2, 1); }
        if (pf) { asm volatile("s_waitcnt vmcnt(4)" ::: "memory"); }
        else    { asm volatile("s_waitcnt vmcnt(0)" ::: "memory"); }
        __builtin_amdgcn_s_barrier();
        __builtin_amdgcn_s_setprio(1);
#pragma unroll
        for (int kk = 0; kk < 2; ++kk)
#pragma unroll
            for (int mi = 0; mi < 4; ++mi)
#pragma unroll
                for (int ni = 0; ni < 2; ++ni)
                    acc[0][mi][1][ni] = __builtin_amdgcn_mfma_f32_16x16x32_bf16(
                        af[mi][kk], bq1[ni][kk], acc[0][mi][1][ni], 0, 0, 0);
        __builtin_amdgcn_s_setprio(0);

        // ---- p2: Q(1,1) — read A1; stage B1' (no barrier) ----
#pragma unroll
        for (int mi = 0; mi < 4; ++mi) {
            af[mi][0] = *(const bf16x8*)(buf + 16384 + aoff[mi]);
            af[mi][1] = *(const bf16x8*)(buf + 16384 + (aoff[mi] ^ 64));
        }
        if (pf) { stage(kn, sb, 3, 0); stage(kn, sb, 3, 1); }
        __builtin_amdgcn_s_setprio(1);
#pragma unroll
        for (int kk = 0; kk < 2; ++kk)
#pragma unroll
            for (int mi = 0; mi < 4; ++mi)
#pragma unroll
                for (int ni = 0; ni < 2; ++ni)
                    acc[1][mi][1][ni] = __builtin_amdgcn_mfma_f32_16x16x32_bf16(
                        af[mi][kk], bq1[ni][kk], acc[1][mi][1][ni], 0, 0, 0);
        __builtin_amdgcn_s_setprio(0);

        // ---- p3: Q(1,0) — no reads; stage A1' ----
        if (pf) { stage(kn, sb, 1, 0); stage(kn, sb, 1, 1); }
        if (pf) { asm volatile("s_waitcnt vmcnt(4)" ::: "memory"); }
        __builtin_amdgcn_s_barrier();
        __builtin_amdgcn_s_setprio(1);
#pragma unroll
        for (int kk = 0; kk < 2; ++kk)
#pragma unroll
            for (int mi = 0; mi < 4; ++mi)
#pragma unroll
                for (int ni = 0; ni < 2; ++ni)
                    acc[1][mi][0][ni] = __builtin_amdgcn_mfma_f32_16x16x32_bf16(
                        af[mi][kk], bq0[ni][kk], acc[1][mi][0][ni], 0, 0, 0);
        __builtin_amdgcn_s_setprio(0);
    }

    // epilogue
    const long cbase = (long)(z / modC) * cHi + (long)(z % modC) * cLo;
#pragma unroll
    for (int qm = 0; qm < 2; ++qm)
#pragma unroll
        for (int mi = 0; mi < 4; ++mi)
#pragma unroll
            for (int qn = 0; qn < 2; ++qn)
#pragma unroll
                for (int ni = 0; ni < 2; ++ni) {
                    const int col = n0 + qn * 128 + wn * 32 + ni * 16 + frow;
                    const int rowb = m0 + qm * 128 + wm * 64 + mi * 16 + fgrp * 4;
#pragma unroll
                    for (int r = 0; r < 4; ++r) {
                        const float v = acc[qm][mi][qn][ni][r];
                        const long idx = cbase + (long)(rowb + r) * ldC + col;
                        if (OUTBF) ((u16*)Cout)[idx] = f2bf(v);
                        else       ((float*)Cout)[idx] = v;
                    }
                }
}

// ======== GEMM4 fused: BM=256, BN=128, BK=64; A = fp32 comb, converted ========
// in-kernel (reg-stage, depth-2, T14 issue-early/write-late). B bf16 gload_lds.
// 3 buffers x (A 32KB | B 16KB). Per tile: 8 A dwordx4 + 2 B gloads = 10 vm.
// vmcnt(12) before convert (drains A(kt+1)); vmcnt(10)+lgkmcnt(0) before end
// barrier (drains B(kt+1), publishes ds_writes). ds_write at inverse-swizzled
// chunk (g^(r&7)) so the r11 conflict-free reader is unchanged.
__global__ __launch_bounds__(512, 1)
void mfma_gemm_big_cf(const float* __restrict__ A, long aZ,
                      const u16* __restrict__ B, long bZ,
                      float* __restrict__ Cout, long cZ,
                      int M, int N, int K)
{
    __shared__ __align__(16) char smem[147456];

    const int z = blockIdx.z;
    const float* Ab = A + (long)z * aZ;
    const char* Bb = (const char*)(B + (long)z * bZ);
    const long ldA = 4096;          // fp32 elements
    const long ldBb = 4096 * 2;     // bytes

    const int m0 = blockIdx.y * 256, n0 = blockIdx.x * 128;
    const int tid = threadIdx.x;
    const int l = tid & 63;
    const int w = tid >> 6;
    const int wm = w >> 1, wn = w & 1;   // 4M x 2N, wave tile 64x64

    // B staging constants (pre-swizzled source, linear dest)
    const int srow = l >> 3;
    const int schunk = (l & 7) ^ srow;
    const long sgo = (long)schunk * 16;
    // A reg-load constants: instr j reads row w*32 + j*4 + (l>>4), bytes (l&15)*16
    const int arj = l >> 4;
    const int ac16 = l & 15;
    const int g = (l & 15) >> 1;    // global chunk 0..7
    const int h2 = l & 1;           // 8B half within chunk
    // frag read constants
    const int frow = l & 15;
    const int fgrp = l >> 4;
    const int fsw = (fgrp ^ (l & 7)) * 16;

    auto stageB = [&](int kt, int j) {
        const int rr = (j * 8 + w) * 8 + srow;
        gload16(Bb + (long)(n0 + rr) * ldBb + (long)kt * 128 + sgo,
                smem + (kt % 3) * 49152 + 32768 + (j * 8 + w) * 1024);
    };
    auto aissue = [&](int kt, float4 (&AR)[8]) {
#pragma unroll
        for (int j = 0; j < 8; ++j)
            AR[j] = *(const float4*)(Ab + (long)(m0 + w * 32 + j * 4 + arj) * ldA +
                                     (long)kt * 64 + ac16 * 4);
    };
    auto aconv = [&](int kt, float4 (&AR)[8]) {
        char* d = smem + (kt % 3) * 49152;
#pragma unroll
        for (int j = 0; j < 8; ++j) {
            const int r = w * 32 + j * 4 + arj;
            ushort4 o;
            o.x = f2bf(AR[j].x); o.y = f2bf(AR[j].y);
            o.z = f2bf(AR[j].z); o.w = f2bf(AR[j].w);
            *(ushort4*)(d + r * 128 + ((g ^ (r & 7)) * 16) + h2 * 8) = o;
        }
    };

    f32x4 acc[4][4];
    const f32x4 zero4 = {0.f, 0.f, 0.f, 0.f};
#pragma unroll
    for (int i = 0; i < 4; ++i)
#pragma unroll
        for (int j = 0; j < 4; ++j) acc[i][j] = zero4;

    int aoff[4], boff[4];
#pragma unroll
    for (int i = 0; i < 4; ++i) {
        aoff[i] = (wm * 64 + i * 16 + frow) * 128 + fsw;
        boff[i] = (wn * 64 + i * 16 + frow) * 128 + fsw;
    }

    float4 aR0[8], aR1[8];
    // prologue: tiles 0,1
    aissue(0, aR0);
    stageB(0, 0); stageB(0, 1);
    aissue(1, aR1);
    stageB(1, 0); stageB(1, 1);
    asm volatile("s_waitcnt vmcnt(12)" ::: "memory");   // A(0) regs landed
    aconv(0, aR0);
    asm volatile("s_waitcnt vmcnt(10)" ::: "memory");   // B(0) landed
    asm volatile("s_waitcnt lgkmcnt(0)" ::: "memory");  // A(0) ds_writes visible
    __builtin_amdgcn_s_barrier();

    const int NT = K >> 6;   // 64, even

#define CF_TILE(KT, ARI, ARC)                                                   \
    {                                                                           \
        const int kt = (KT);                                                    \
        const bool pf2 = (kt + 2) < NT, pf1 = (kt + 1) < NT;                    \
        if (pf2) { aissue(kt + 2, ARI); stageB(kt + 2, 0); stageB(kt + 2, 1); } \
        if (pf1) {                                                              \
            if (pf2) { asm volatile("s_waitcnt vmcnt(12)" ::: "memory"); }      \
            else     { asm volatile("s_waitcnt vmcnt(2)" ::: "memory"); }       \
            aconv(kt + 1, ARC);                                                 \
        }                                                                       \
        const char* bufA = smem + (kt % 3) * 49152;                             \
        const char* bufB = bufA + 32768;                                        \
        bf16x8 af[4][2], bfr[4][2];                                             \
        _Pragma("unroll")                                                       \
        for (int mi = 0; mi < 4; ++mi) {                                        \
            af[mi][0] = *(const bf16x8*)(bufA + aoff[mi]);                      \
            af[mi][1] = *(const bf16x8*)(bufA + (aoff[mi] ^ 64));               \
        }                                                                       \
        _Pragma("unroll")                                                       \
        for (int ni = 0; ni < 4; ++ni) {                                        \
            bfr[ni][0] = *(const bf16x8*)(bufB + boff[ni]);                     \
            bfr[ni][1] = *(const bf16x8*)(bufB + (boff[ni] ^ 64));              \
        }                                                                       \
        __builtin_amdgcn_s_setprio(1);                                          \
        _Pragma("unroll")                                                       \
        for (int kk = 0; kk < 2; ++kk)                                          \
            _Pragma("unroll")                                                   \
            for (int mi = 0; mi < 4; ++mi)                                      \
                _Pragma("unroll")                                               \
                for (int ni = 0; ni < 4; ++ni)                                  \
                    acc[mi][ni] = __builtin_amdgcn_mfma_f32_16x16x32_bf16(      \
                        af[mi][kk], bfr[ni][kk], acc[mi][ni], 0, 0, 0);         \
        __builtin_amdgcn_s_setprio(0);                                          \
        if (pf1 && pf2) { asm volatile("s_waitcnt vmcnt(10)" ::: "memory"); }   \
        else            { asm volatile("s_waitcnt vmcnt(0)" ::: "memory"); }    \
        asm volatile("s_waitcnt lgkmcnt(0)" ::: "memory");                      \
        __builtin_amdgcn_s_barrier();                                           \
    }

    for (int it = 0; it < NT / 2; ++it) {
        CF_TILE(2 * it,     aR0, aR1);
        CF_TILE(2 * it + 1, aR1, aR0);
    }
#undef CF_TILE

    // epilogue (fp32 out)
    const long cbase = (long)z * cZ;
#pragma unroll
    for (int mi = 0; mi < 4; ++mi) {
#pragma unroll
        for (int ni = 0; ni < 4; ++ni) {
            const int col = n0 + wn * 64 + ni * 16 + frow;
            const int rowb = m0 + wm * 64 + mi * 16 + fgrp * 4;
#pragma unroll
            for (int r = 0; r < 4; ++r) {
                Cout[cbase + (long)(rowb + r) * 2048 + col] = acc[mi][ni][r];
            }
        }
    }
}

extern "C" void kernel_launch(void* const* d_in, const int* in_sizes, int n_in,
                              void* d_out, int out_size, void* d_ws, size_t ws_size,
                              hipStream_t stream) {
    const float* x    = (const float*)d_in[0];
    const float* mask = (const float*)d_in[1];
    const float* comb = (const float*)d_in[2];
    const float* W1   = (const float*)d_in[3];
    const float* b1   = (const float*)d_in[4];
    const float* W2   = (const float*)d_in[5];
    const float* b2   = (const float*)d_in[6];
    float* out = (float*)d_out;

    char* ws = (char*)d_ws;
    u16* buf0 = (u16*)ws;                    // maskT [16][C][T]; P partials later
    u16* xT   = (u16*)(ws + 33554432);
    u16* W1b2 = (u16*)(ws + 33554432);       // overwrites dead xT after GEMM1
    u16* W2b  = (u16*)(ws + 58720256);
    u16* xe   = (u16*)(ws + 67108864);
    u16* h    = (u16*)(ws + 100663296);
    u16* yT   = xe;
    float* P  = (float*)ws;                  // GEMM2 fp32 partials

    transpose_conv<<<dim3(DD / 32, TT / 32, BB), 256, 0, stream>>>(
        x, (long)TT * DD, 0L, 1, (long)DD, xT, (long)DD * TT, (long)TT);
    transpose_conv<<<dim3(CCv / 32, TT / 32, BB * EE), 256, 0, stream>>>(
        mask, (long)TT * EE * CCv, (long)CCv, EE, (long)EE * CCv,
        buf0, (long)CCv * TT, (long)TT);
    conv_cast<<<(int)((8L * DD * OO1) / 1024), 256, 0, stream>>>(W2, W2b, 8L * DD * OO1);

    // GEMM1: xe[z][c][d] = sum_t maskT[z][c][t]*xT[b][d][t]; M=512,N=2048,K=2048,Z=16
    mfma_gemm_256<1><<<dim3(DD / 256, CCv / 256, 16), 512, 0, stream>>>(
        buf0, 2048, 1048576L, 0L, 1,
        xT,   2048, 4194304L, 0L, 8,
        xe,   2048, 1048576L, 0L, 1,
        CCv, DD, TT);

    dup_cast<<<4096, 256, 0, stream>>>(W1, W1b2, 4194304L);

    // GEMM2 split-K=2: z' = 2*z + kh
    mfma_gemm<0, 0><<<dim3(OO1 / 128, CCv / 128, 32), 256, 0, stream>>>(
        xe,   2048, 1048576L, 1024L, 2,
        W1b2, 2048, 524288L, 1024L, 2,
        P,    256, 131072L, 4194304L, 2,
        nullptr, 0L, 1, CCv, OO1, 1024);

    gelu_fuse<<<2048, 256, 0, stream>>>(P, b1, h);

    // GEMM3T: yT[b][d][e*512+c] = W2.h^T + b2 ; M=2048,N=512,K=256,Z=16 (small kernel)
    mfma_gemm<3, 1><<<dim3(CCv / 128, DD / 128, 16), 256, 0, stream>>>(
        W2b, 256, 0L, 524288L, 8,
        h,   256, 131072L, 0L, 1,
        yT,  4096, 8388608L, 512L, 8,
        b2, 0L, 1, DD, CCv, OO1);

    // GEMM4 (comb-cast fused): out[b][t][d] = sum_ec comb[b][t][ec]*yT[b][d][ec]
    mfma_gemm_big_cf<<<dim3(DD / 128, TT / 256, BB), 512, 0, stream>>>(
        comb, 8388608L,
        yT,   8388608L,
        out,  4194304L,
        TT, DD, EE * CCv);
}

// Round 13
// 244.995 us; speedup vs baseline: 1.2966x; 1.2966x over previous
//
#include <hip/hip_runtime.h>
#include <math.h>

#define BB 2
#define TT 2048
#define DD 2048
#define EE 8
#define CCv 512
#define OO1 256

typedef unsigned short u16;
typedef __bf16 bf16x8 __attribute__((ext_vector_type(8)));
typedef float f32x4 __attribute__((ext_vector_type(4)));

__device__ __forceinline__ u16 f2bf(float f) {
    unsigned u = __float_as_uint(f);
    unsigned r = (u + 0x7fffu + ((u >> 16) & 1u)) >> 16;
    return (u16)r;
}

__device__ __forceinline__ void gload16(const void* g, void* s) {
    __builtin_amdgcn_global_load_lds(
        (const __attribute__((address_space(1))) void*)g,
        (__attribute__((address_space(3))) void*)s, 16, 0, 0);
}

// XCD-aware bijective block remap (T1, m204 form; grid size % 8 == 0).
__device__ __forceinline__ void xcd_swizzle(int& bx, int& by, int& bz) {
    const int nx = gridDim.x, ny = gridDim.y;
    const int nwg = nx * ny * gridDim.z;
    const int hw = blockIdx.x + nx * (blockIdx.y + ny * blockIdx.z);
    const int q = nwg >> 3;
    const int lid = (hw & 7) * q + (hw >> 3);
    bx = lid % nx;
    const int rest = lid / nx;
    by = rest % ny;
    bz = rest / ny;
}

// ---------------- fp32 -> bf16 straight convert (vectorized) ----------------
__global__ __launch_bounds__(256) void conv_cast(const float* __restrict__ in,
                                                 u16* __restrict__ out, long n) {
    long i = ((long)blockIdx.x * 256 + threadIdx.x) * 4;
    float4 v = *(const float4*)&in[i];
    ushort4 o; o.x = f2bf(v.x); o.y = f2bf(v.y); o.z = f2bf(v.z); o.w = f2bf(v.w);
    *(ushort4*)&out[i] = o;
}

// ---------------- fp32 -> bf16 convert, write TWO copies (W1 per-batch dup) --
__global__ __launch_bounds__(256) void dup_cast(const float* __restrict__ in,
                                                u16* __restrict__ out, long dup) {
    long i = ((long)blockIdx.x * 256 + threadIdx.x) * 4;
    float4 v = *(const float4*)&in[i];
    ushort4 o; o.x = f2bf(v.x); o.y = f2bf(v.y); o.z = f2bf(v.z); o.w = f2bf(v.w);
    *(ushort4*)&out[i] = o;
    *(ushort4*)&out[i + dup] = o;
}

// ---------------- h = GELU(P0 + P1 + b1) -> bf16 (GEMM2 split-K fuse) -------
__global__ __launch_bounds__(256) void gelu_fuse(const float* __restrict__ P,
                                                 const float* __restrict__ b1,
                                                 u16* __restrict__ h) {
    long i = ((long)blockIdx.x * 256 + threadIdx.x) * 4;   // [z][c][o] flat
    const int o = (int)(i & 255);
    const int e = (int)((i >> 17) & 7);
    float4 a = *(const float4*)&P[i];
    float4 b = *(const float4*)&P[i + 4194304];
    float4 bb = *(const float4*)&b1[e * 256 + o];
    float r0 = a.x + b.x + bb.x, r1 = a.y + b.y + bb.y;
    float r2 = a.z + b.z + bb.z, r3 = a.w + b.w + bb.w;
    ushort4 o4;
    o4.x = f2bf(0.5f * r0 * (1.0f + erff(r0 * 0.70710678118654752f)));
    o4.y = f2bf(0.5f * r1 * (1.0f + erff(r1 * 0.70710678118654752f)));
    o4.z = f2bf(0.5f * r2 * (1.0f + erff(r2 * 0.70710678118654752f)));
    o4.w = f2bf(0.5f * r3 * (1.0f + erff(r3 * 0.70710678118654752f)));
    *(ushort4*)&h[i] = o4;
}

// ---------------- tiled transpose + convert: out[z][c][t] = in[z][t][c] -----
__global__ __launch_bounds__(256) void transpose_conv(
    const float* __restrict__ in, long inHi, long inLo, int modZ, long sIn,
    u16* __restrict__ out, long outZ, long sOut)
{
    __shared__ float tile[32][33];
    const int z = blockIdx.z;
    const float* ib = in + (long)(z / modZ) * inHi + (long)(z % modZ) * inLo;
    u16* ob = out + (long)z * outZ;
    const int t0 = blockIdx.y * 32, c0 = blockIdx.x * 32;
    const int tid = threadIdx.x;
    const int r = tid >> 3, c4 = (tid & 7) * 4;

    float4 v = *(const float4*)&ib[(long)(t0 + r) * sIn + c0 + c4];
    tile[r][c4 + 0] = v.x; tile[r][c4 + 1] = v.y;
    tile[r][c4 + 2] = v.z; tile[r][c4 + 3] = v.w;
    __syncthreads();

    const int oc = tid >> 3, t4 = (tid & 7) * 4;
    ushort4 o;
    o.x = f2bf(tile[t4 + 0][oc]);
    o.y = f2bf(tile[t4 + 1][oc]);
    o.z = f2bf(tile[t4 + 2][oc]);
    o.w = f2bf(tile[t4 + 3][oc]);
    *(ushort4*)&ob[(long)(c0 + oc) * sOut + t0 + t4] = o;
}

// ---------------- small 128x128 m97-structure GEMM (GEMM2 split-K / GEMM3) --
template<int EPI, int OUTBF>
__global__ __launch_bounds__(256)
void mfma_gemm(const u16* __restrict__ A, long ldA, long aHi, long aLo, int modA,
               const u16* __restrict__ B, long ldB, long bHi, long bLo, int modB,
               void* __restrict__ Cout, long ldC, long cHi, long cLo, int modC,
               const float* __restrict__ bias, long biasLo, int modBias,
               int M, int N, int K)
{
    __shared__ __align__(16) char smem[32768];
    char* smA = smem;
    char* smB = smem + 16384;

    const int z = blockIdx.z;
    const char* Ab = (const char*)(A + (long)(z / modA) * aHi + (long)(z % modA) * aLo);
    const char* Bb = (const char*)(B + (long)(z / modB) * bHi + (long)(z % modB) * bLo);
    const long ldAb = ldA * 2, ldBb = ldB * 2;

    const int m0 = blockIdx.y * 128, n0 = blockIdx.x * 128;
    const int tid = threadIdx.x;
    const int l = tid & 63;
    const int w = tid >> 6;
    const int wm = w >> 1, wn = w & 1;

    const int srow = l >> 3;
    const int schunk = (l & 7) ^ srow;
    const int frow = l & 15;
    const int fgrp = l >> 4;
    const int fch0 = fgrp ^ (l & 7);

    int aoff[4], boff[4];
#pragma unroll
    for (int i = 0; i < 4; ++i) {
        aoff[i] = (wm * 64 + i * 16 + frow) * 128 + fch0 * 16;
        boff[i] = (wn * 64 + i * 16 + frow) * 128 + fch0 * 16;
    }

    f32x4 acc[4][4];
    const f32x4 zero4 = {0.f, 0.f, 0.f, 0.f};
#pragma unroll
    for (int i = 0; i < 4; ++i)
#pragma unroll
        for (int j = 0; j < 4; ++j) acc[i][j] = zero4;

    const long sgo = (long)schunk * 16;

    for (int k0 = 0; k0 < K; k0 += 64) {
        const long kb = (long)k0 * 2;
#pragma unroll
        for (int j = 0; j < 4; ++j) {
            const int rr = (j * 4 + w) * 8 + srow;
            gload16(Ab + (long)(m0 + rr) * ldAb + kb + sgo, smA + (j * 4 + w) * 1024);
            gload16(Bb + (long)(n0 + rr) * ldBb + kb + sgo, smB + (j * 4 + w) * 1024);
        }
        __syncthreads();
#pragma unroll
        for (int kk = 0; kk < 2; ++kk) {
            const int kx = kk * 64;
            bf16x8 af[4], bfr[4];
#pragma unroll
            for (int i = 0; i < 4; ++i) af[i] = *(const bf16x8*)(smA + (aoff[i] ^ kx));
#pragma unroll
            for (int i = 0; i < 4; ++i) bfr[i] = *(const bf16x8*)(smB + (boff[i] ^ kx));
#pragma unroll
            for (int mi = 0; mi < 4; ++mi)
#pragma unroll
                for (int ni = 0; ni < 4; ++ni)
                    acc[mi][ni] = __builtin_amdgcn_mfma_f32_16x16x32_bf16(
                        af[mi], bfr[ni], acc[mi][ni], 0, 0, 0);
        }
        __syncthreads();
    }

    const long cbase = (long)(z / modC) * cHi + (long)(z % modC) * cLo;
    const float* biasB = (EPI != 0) ? (bias + (long)(z % modBias) * biasLo) : nullptr;
#pragma unroll
    for (int mi = 0; mi < 4; ++mi) {
#pragma unroll
        for (int ni = 0; ni < 4; ++ni) {
            const int col = n0 + wn * 64 + ni * 16 + frow;
            const int rowb = m0 + wm * 64 + mi * 16 + fgrp * 4;
#pragma unroll
            for (int r = 0; r < 4; ++r) {
                float v = acc[mi][ni][r];
                const int row = rowb + r;
                if (EPI == 3) v += biasB[row];
                const long idx = cbase + (long)row * ldC + col;
                if (OUTBF) ((u16*)Cout)[idx] = f2bf(v);
                else       ((float*)Cout)[idx] = v;
            }
        }
    }
}

// ---------------- 256x256 pipelined GEMM (GEMM1), r11 + XCD swizzle ---------
template<int OUTBF>
__global__ __launch_bounds__(512, 2)
void mfma_gemm_256(const u16* __restrict__ A, long ldA, long aHi, long aLo, int modA,
                   const u16* __restrict__ B, long ldB, long bHi, long bLo, int modB,
                   void* __restrict__ Cout, long ldC, long cHi, long cLo, int modC,
                   int M, int N, int K)
{
    __shared__ __align__(16) char smem[131072];   // 2 x (A0 A1 B0 B1) x 16KB

    int sbx, sby, sbz;
    xcd_swizzle(sbx, sby, sbz);

    const int z = sbz;
    const char* Ab = (const char*)(A + (long)(z / modA) * aHi + (long)(z % modA) * aLo);
    const char* Bb = (const char*)(B + (long)(z / modB) * bHi + (long)(z % modB) * bLo);
    const long ldAb = ldA * 2, ldBb = ldB * 2;

    const int m0 = sby * 256, n0 = sbx * 256;
    const int tid = threadIdx.x;
    const int l = tid & 63;
    const int w = tid >> 6;
    const int wm = w >> 2, wn = w & 3;   // 2M x 4N

    const int srow = l >> 3;
    const int schunk = (l & 7) ^ srow;
    const long sgo = (long)schunk * 16;
    const int frow = l & 15, fgrp = l >> 4;
    const int cs0 = (fgrp ^ (l & 7)) * 16;

    auto stage = [&](int kt, int bsel, int half, int j) {
        const int rr = (w * 2 + j) * 8 + srow;
        const char* gb = (half < 2) ? Ab : Bb;
        const long ld = (half < 2) ? ldAb : ldBb;
        const int gr = ((half < 2) ? m0 + half * 128 : n0 + (half - 2) * 128) + rr;
        gload16(gb + (long)gr * ld + (long)kt * 128 + sgo,
                smem + bsel * 65536 + half * 16384 + (w * 2 + j) * 1024);
    };

    f32x4 acc[2][4][2][2];
    const f32x4 zero4 = {0.f, 0.f, 0.f, 0.f};
#pragma unroll
    for (int qm = 0; qm < 2; ++qm)
#pragma unroll
        for (int mi = 0; mi < 4; ++mi)
#pragma unroll
            for (int qn = 0; qn < 2; ++qn)
#pragma unroll
                for (int ni = 0; ni < 2; ++ni) acc[qm][mi][qn][ni] = zero4;

    int aoff[4], boff[2];
#pragma unroll
    for (int mi = 0; mi < 4; ++mi) aoff[mi] = (wm * 64 + mi * 16 + frow) * 128 + cs0;
#pragma unroll
    for (int ni = 0; ni < 2; ++ni) boff[ni] = (wn * 32 + ni * 16 + frow) * 128 + cs0;

    // prologue: stage tile 0 (order A0,B0,B1,A1)
    stage(0, 0, 0, 0); stage(0, 0, 0, 1);
    stage(0, 0, 2, 0); stage(0, 0, 2, 1);
    stage(0, 0, 3, 0); stage(0, 0, 3, 1);
    stage(0, 0, 1, 0); stage(0, 0, 1, 1);
    asm volatile("s_waitcnt vmcnt(4)" ::: "memory");   // A0,B0 landed
    __builtin_amdgcn_s_barrier();

    const int NT = K >> 6;
    for (int kt = 0; kt < NT; ++kt) {
        const char* buf = smem + (kt & 1) * 65536;
        const int sb = (kt & 1) ^ 1;
        const bool pf = (kt + 1) < NT;
        const int kn = kt + 1;
        bf16x8 af[4][2], bq0[2][2], bq1[2][2];

        // ---- p0: Q(0,0) — read A0 + B0; stage A0' ----
#pragma unroll
        for (int mi = 0; mi < 4; ++mi) {
            af[mi][0] = *(const bf16x8*)(buf + aoff[mi]);
            af[mi][1] = *(const bf16x8*)(buf + (aoff[mi] ^ 64));
        }
#pragma unroll
        for (int ni = 0; ni < 2; ++ni) {
            bq0[ni][0] = *(const bf16x8*)(buf + 32768 + boff[ni]);
            bq0[ni][1] = *(const bf16x8*)(buf + 32768 + (boff[ni] ^ 64));
        }
        if (pf) { stage(kn, sb, 0, 0); stage(kn, sb, 0, 1); }
        if (pf) { asm volatile("s_waitcnt vmcnt(4)" ::: "memory"); }
        else    { asm volatile("s_waitcnt vmcnt(2)" ::: "memory"); }
        __builtin_amdgcn_s_barrier();
        __builtin_amdgcn_s_setprio(1);
#pragma unroll
        for (int kk = 0; kk < 2; ++kk)
#pragma unroll
            for (int mi = 0; mi < 4; ++mi)
#pragma unroll
                for (int ni = 0; ni < 2; ++ni)
                    acc[0][mi][0][ni] = __builtin_amdgcn_mfma_f32_16x16x32_bf16(
                        af[mi][kk], bq0[ni][kk], acc[0][mi][0][ni], 0, 0, 0);
        __builtin_amdgcn_s_setprio(0);

        // ---- p1: Q(0,1) — read B1; stage B0' ----
#pragma unroll
        for (int ni = 0; ni < 2; ++ni) {
            bq1[ni][0] = *(const bf16x8*)(buf + 49152 + boff[ni]);
            bq1[ni][1] = *(const bf16x8*)(buf + 49152 + (boff[ni] ^ 64));
        }
        if (pf) { stage(kn, sb, 2, 0); stage(kn, sb, 2, 1); }
        if (pf) { asm volatile("s_waitcnt vmcnt(4)" ::: "memory"); }
        else    { asm volatile("s_waitcnt vmcnt(0)" ::: "memory"); }
        __builtin_amdgcn_s_barrier();
        __builtin_amdgcn_s_setprio(1);
#pragma unroll
        for (int kk = 0; kk < 2; ++kk)
#pragma unroll
            for (int mi = 0; mi < 4; ++mi)
#pragma unroll
                for (int ni = 0; ni < 2; ++ni)
                    acc[0][mi][1][ni] = __builtin_amdgcn_mfma_f32_16x16x32_bf16(
                        af[mi][kk], bq1[ni][kk], acc[0][mi][1][ni], 0, 0, 0);
        __builtin_amdgcn_s_setprio(0);

        // ---- p2: Q(1,1) — read A1; stage B1' (no barrier) ----
#pragma unroll
        for (int mi = 0; mi < 4; ++mi) {
            af[mi][0] = *(const bf16x8*)(buf + 16384 + aoff[mi]);
            af[mi][1] = *(const bf16x8*)(buf + 16384 + (aoff[mi] ^ 64));
        }
        if (pf) { stage(kn, sb, 3, 0); stage(kn, sb, 3, 1); }
        __builtin_amdgcn_s_setprio(1);
#pragma unroll
        for (int kk = 0; kk < 2; ++kk)
#pragma unroll
            for (int mi = 0; mi < 4; ++mi)
#pragma unroll
                for (int ni = 0; ni < 2; ++ni)
                    acc[1][mi][1][ni] = __builtin_amdgcn_mfma_f32_16x16x32_bf16(
                        af[mi][kk], bq1[ni][kk], acc[1][mi][1][ni], 0, 0, 0);
        __builtin_amdgcn_s_setprio(0);

        // ---- p3: Q(1,0) — no reads; stage A1' ----
        if (pf) { stage(kn, sb, 1, 0); stage(kn, sb, 1, 1); }
        if (pf) { asm volatile("s_waitcnt vmcnt(4)" ::: "memory"); }
        __builtin_amdgcn_s_barrier();
        __builtin_amdgcn_s_setprio(1);
#pragma unroll
        for (int kk = 0; kk < 2; ++kk)
#pragma unroll
            for (int mi = 0; mi < 4; ++mi)
#pragma unroll
                for (int ni = 0; ni < 2; ++ni)
                    acc[1][mi][0][ni] = __builtin_amdgcn_mfma_f32_16x16x32_bf16(
                        af[mi][kk], bq0[ni][kk], acc[1][mi][0][ni], 0, 0, 0);
        __builtin_amdgcn_s_setprio(0);
    }

    // epilogue
    const long cbase = (long)(z / modC) * cHi + (long)(z % modC) * cLo;
#pragma unroll
    for (int qm = 0; qm < 2; ++qm)
#pragma unroll
        for (int mi = 0; mi < 4; ++mi)
#pragma unroll
            for (int qn = 0; qn < 2; ++qn)
#pragma unroll
                for (int ni = 0; ni < 2; ++ni) {
                    const int col = n0 + qn * 128 + wn * 32 + ni * 16 + frow;
                    const int rowb = m0 + qm * 128 + wm * 64 + mi * 16 + fgrp * 4;
#pragma unroll
                    for (int r = 0; r < 4; ++r) {
                        const float v = acc[qm][mi][qn][ni][r];
                        const long idx = cbase + (long)(rowb + r) * ldC + col;
                        if (OUTBF) ((u16*)Cout)[idx] = f2bf(v);
                        else       ((float*)Cout)[idx] = v;
                    }
                }
}

// -------- BIG pipelined GEMM: BM=256, BN=128, BK=64 (GEMM4), r11 + swizzle --
template<int EPI, int OUTBF>
__global__ __launch_bounds__(512, 2)
void mfma_gemm_big(const u16* __restrict__ A, long ldA, long aHi, long aLo, int modA,
                   const u16* __restrict__ B, long ldB, long bHi, long bLo, int modB,
                   void* __restrict__ Cout, long ldC, long cHi, long cLo, int modC,
                   const float* __restrict__ bias,
                   int M, int N, int K)
{
    __shared__ __align__(16) char smem[147456];

    int sbx, sby, sbz;
    xcd_swizzle(sbx, sby, sbz);

    const int z = sbz;
    const char* Ab = (const char*)(A + (long)(z / modA) * aHi + (long)(z % modA) * aLo);
    const char* Bb = (const char*)(B + (long)(z / modB) * bHi + (long)(z % modB) * bLo);
    const long ldAb = ldA * 2, ldBb = ldB * 2;

    const int m0 = sby * 256, n0 = sbx * 128;
    const int tid = threadIdx.x;
    const int l = tid & 63;
    const int w = tid >> 6;
    const int wm = w >> 1, wn = w & 1;   // 4M x 2N -> wave tile 64x64

    const int srow = l >> 3;
    const int schunk = (l & 7) ^ srow;
    const long sgo = (long)schunk * 16;
    const int frow = l & 15;
    const int fgrp = l >> 4;
    const int fsw = (fgrp ^ (l & 7)) * 16;

    auto stageA = [&](int kt, int bsel, int j) {
        const int rr = (j * 8 + w) * 8 + srow;
        gload16(Ab + (long)(m0 + rr) * ldAb + (long)kt * 128 + sgo,
                smem + bsel * 49152 + (j * 8 + w) * 1024);
    };
    auto stageB = [&](int kt, int bsel, int j) {
        const int rr = (j * 8 + w) * 8 + srow;
        gload16(Bb + (long)(n0 + rr) * ldBb + (long)kt * 128 + sgo,
                smem + bsel * 49152 + 32768 + (j * 8 + w) * 1024);
    };

    f32x4 acc[4][4];
    const f32x4 zero4 = {0.f, 0.f, 0.f, 0.f};
#pragma unroll
    for (int i = 0; i < 4; ++i)
#pragma unroll
        for (int j = 0; j < 4; ++j) acc[i][j] = zero4;

    int aoff[4], boff[4];
#pragma unroll
    for (int i = 0; i < 4; ++i) {
        aoff[i] = (wm * 64 + i * 16 + frow) * 128 + fsw;
        boff[i] = (wn * 64 + i * 16 + frow) * 128 + fsw;
    }

#pragma unroll
    for (int j = 0; j < 4; ++j) stageA(0, 0, j);
#pragma unroll
    for (int j = 0; j < 2; ++j) stageB(0, 0, j);
#pragma unroll
    for (int j = 0; j < 4; ++j) stageA(1, 1, j);
#pragma unroll
    for (int j = 0; j < 2; ++j) stageB(1, 1, j);
    asm volatile("s_waitcnt vmcnt(6)" ::: "memory");
    __builtin_amdgcn_s_barrier();

    const int NT = K >> 6;
    int bc = 0;
    int sc = 2;
    for (int kt = 0; kt < NT; ++kt) {
        const char* bufA = smem + bc * 49152;
        const char* bufB = bufA + 32768;
        const bool pf = (kt + 2) < NT;
        const int kpf = kt + 2;

        if (pf) {
            stageA(kpf, sc, 0); stageA(kpf, sc, 1);
            stageA(kpf, sc, 2); stageA(kpf, sc, 3);
            stageB(kpf, sc, 0); stageB(kpf, sc, 1);
        }

        bf16x8 af[4][2], bfr[4][2];
#pragma unroll
        for (int mi = 0; mi < 4; ++mi) {
            af[mi][0] = *(const bf16x8*)(bufA + aoff[mi]);
            af[mi][1] = *(const bf16x8*)(bufA + (aoff[mi] ^ 64));
        }
#pragma unroll
        for (int ni = 0; ni < 4; ++ni) {
            bfr[ni][0] = *(const bf16x8*)(bufB + boff[ni]);
            bfr[ni][1] = *(const bf16x8*)(bufB + (boff[ni] ^ 64));
        }

        __builtin_amdgcn_s_setprio(1);
#pragma unroll
        for (int kk = 0; kk < 2; ++kk)
#pragma unroll
            for (int mi = 0; mi < 4; ++mi)
#pragma unroll
                for (int ni = 0; ni < 4; ++ni)
                    acc[mi][ni] = __builtin_amdgcn_mfma_f32_16x16x32_bf16(
                        af[mi][kk], bfr[ni][kk], acc[mi][ni], 0, 0, 0);
        __builtin_amdgcn_s_setprio(0);

        if (pf) { asm volatile("s_waitcnt vmcnt(6)" ::: "memory"); }
        else    { asm volatile("s_waitcnt vmcnt(0)" ::: "memory"); }
        __builtin_amdgcn_s_barrier();

        bc = (bc == 2) ? 0 : bc + 1;
        sc = (sc == 2) ? 0 : sc + 1;
    }

    const long cbase = (long)(z / modC) * cHi + (long)(z % modC) * cLo;
#pragma unroll
    for (int mi = 0; mi < 4; ++mi) {
#pragma unroll
        for (int ni = 0; ni < 4; ++ni) {
            const int col = n0 + wn * 64 + ni * 16 + frow;
            const int rowb = m0 + wm * 64 + mi * 16 + fgrp * 4;
#pragma unroll
            for (int r = 0; r < 4; ++r) {
                float v = acc[mi][ni][r];
                if (EPI == 3) v += bias[rowb + r];
                const long idx = cbase + (long)(rowb + r) * ldC + col;
                if (OUTBF) ((u16*)Cout)[idx] = f2bf(v);
                else       ((float*)Cout)[idx] = v;
            }
        }
    }
}

extern "C" void kernel_launch(void* const* d_in, const int* in_sizes, int n_in,
                              void* d_out, int out_size, void* d_ws, size_t ws_size,
                              hipStream_t stream) {
    const float* x    = (const float*)d_in[0];
    const float* mask = (const float*)d_in[1];
    const float* comb = (const float*)d_in[2];
    const float* W1   = (const float*)d_in[3];
    const float* b1   = (const float*)d_in[4];
    const float* W2   = (const float*)d_in[5];
    const float* b2   = (const float*)d_in[6];
    float* out = (float*)d_out;

    char* ws = (char*)d_ws;
    u16* buf0 = (u16*)ws;
    u16* xT   = (u16*)(ws + 33554432);
    u16* W1b2 = (u16*)(ws + 33554432);       // overwrites dead xT after GEMM1
    u16* W2b  = (u16*)(ws + 58720256);
    u16* xe   = (u16*)(ws + 67108864);
    u16* h    = (u16*)(ws + 100663296);
    u16* yT   = xe;
    float* P  = (float*)ws;                  // GEMM2 fp32 partials

    transpose_conv<<<dim3(DD / 32, TT / 32, BB), 256, 0, stream>>>(
        x, (long)TT * DD, 0L, 1, (long)DD, xT, (long)DD * TT, (long)TT);
    transpose_conv<<<dim3(CCv / 32, TT / 32, BB * EE), 256, 0, stream>>>(
        mask, (long)TT * EE * CCv, (long)CCv, EE, (long)EE * CCv,
        buf0, (long)CCv * TT, (long)TT);
    conv_cast<<<(int)((8L * DD * OO1) / 1024), 256, 0, stream>>>(W2, W2b, 8L * DD * OO1);

    // GEMM1: xe[z][c][d] = sum_t maskT[z][c][t]*xT[b][d][t]; M=512,N=2048,K=2048,Z=16
    mfma_gemm_256<1><<<dim3(DD / 256, CCv / 256, 16), 512, 0, stream>>>(
        buf0, 2048, 1048576L, 0L, 1,
        xT,   2048, 4194304L, 0L, 8,
        xe,   2048, 1048576L, 0L, 1,
        CCv, DD, TT);

    dup_cast<<<4096, 256, 0, stream>>>(W1, W1b2, 4194304L);

    // GEMM2 split-K=2: z' = 2*z + kh
    mfma_gemm<0, 0><<<dim3(OO1 / 128, CCv / 128, 32), 256, 0, stream>>>(
        xe,   2048, 1048576L, 1024L, 2,
        W1b2, 2048, 524288L, 1024L, 2,
        P,    256, 131072L, 4194304L, 2,
        nullptr, 0L, 1, CCv, OO1, 1024);

    gelu_fuse<<<2048, 256, 0, stream>>>(P, b1, h);

    // GEMM3T: yT[b][d][e*512+c] = W2.h^T + b2 ; M=2048,N=512,K=256,Z=16 (small kernel)
    mfma_gemm<3, 1><<<dim3(CCv / 128, DD / 128, 16), 256, 0, stream>>>(
        W2b, 256, 0L, 524288L, 8,
        h,   256, 131072L, 0L, 1,
        yT,  4096, 8388608L, 512L, 8,
        b2, 0L, 1, DD, CCv, OO1);

    conv_cast<<<(int)((2L * TT * EE * CCv) / 1024), 256, 0, stream>>>(
        comb, buf0, 2L * TT * EE * CCv);

    // GEMM4: out[b][t][d] = sum_ec comb[b][t][ec]*yT[b][d][ec]; M=2048,N=2048,K=4096,Z=2
    mfma_gemm_big<0, 0><<<dim3(DD / 128, TT / 256, BB), 512, 0, stream>>>(
        buf0, 4096, 8388608L, 0L, 1,
        yT,   4096, 8388608L, 0L, 1,
        out,  2048, 4194304L, 0L, 1,
        nullptr, TT, DD, EE * CCv);
}